// Round 4
// baseline (649.444 us; speedup 1.0000x reference)
//
#include <hip/hip_runtime.h>
#include <stdint.h>

#define NN 8192
#define FIN 512
#define FOUT 256
#define ALPHA 0.2f
#define KSPLIT 8
#define KSLICE (NN / KSPLIT)   // 1024
#define BK 32
#define ITERS (KSLICE / BK)    // 32

typedef float f32x4 __attribute__((ext_vector_type(4)));
typedef short s16x8 __attribute__((ext_vector_type(8)));

__device__ __forceinline__ uint16_t f2bf(float f) {
  union { float f; uint32_t u; } v; v.f = f;
  uint32_t u = v.u + 0x7fffu + ((v.u >> 16) & 1u);
  return (uint16_t)(u >> 16);
}

// LDS-only barrier: waits DS ops, does NOT drain vmcnt -> global prefetches
// stay in flight across the barrier (m131-m141: __syncthreads drains vmcnt(0)).
__device__ __forceinline__ void lds_barrier() {
  asm volatile("s_waitcnt lgkmcnt(0)\n\ts_barrier" ::: "memory");
}

// ---------------- 1. wa1/wa2 = W @ a1 / a2 (fp32) ----------------
__global__ __launch_bounds__(256) void k_wa(const float* __restrict__ W,
                                            const float* __restrict__ a,
                                            float* __restrict__ wa1, float* __restrict__ wa2) {
  __shared__ float a1[256], a2[256];
  int tid = threadIdx.x;
  a1[tid] = a[tid];
  a2[tid] = a[tid + 256];
  __syncthreads();
  int m = blockIdx.x * 256 + tid;   // 0..511
  const float* wrow = W + (size_t)m * FOUT;
  float s1 = 0.f, s2 = 0.f;
  for (int k = 0; k < FOUT; k += 4) {
    f32x4 v = *(const f32x4*)(wrow + k);
#pragma unroll
    for (int i = 0; i < 4; i++) {
      s1 += v[i] * a1[k + i];
      s2 += v[i] * a2[k + i];
    }
  }
  wa1[m] = s1; wa2[m] = s2;
}

// ---------------- 2. f1/f2 = x @ wa1/wa2 (fp32, exact logits) ----------------
__global__ __launch_bounds__(256) void k_f1f2(const float* __restrict__ x,
                                              const float* __restrict__ wa1,
                                              const float* __restrict__ wa2,
                                              float* __restrict__ f1, float* __restrict__ f2) {
  __shared__ float s1[512], s2[512];
  int tid = threadIdx.x;
  s1[tid] = wa1[tid]; s1[tid + 256] = wa1[tid + 256];
  s2[tid] = wa2[tid]; s2[tid + 256] = wa2[tid + 256];
  __syncthreads();
  int w = tid >> 6, l = tid & 63;
  int row = blockIdx.x * 4 + w;
  const float* xr = x + (size_t)row * FIN + l * 8;
  f32x4 v0 = *(const f32x4*)xr;
  f32x4 v1 = *(const f32x4*)(xr + 4);
  int kb = l * 8;
  float d1 = 0.f, d2 = 0.f;
#pragma unroll
  for (int i = 0; i < 4; i++) {
    d1 += v0[i] * s1[kb + i] + v1[i] * s1[kb + 4 + i];
    d2 += v0[i] * s2[kb + i] + v1[i] * s2[kb + 4 + i];
  }
#pragma unroll
  for (int off = 32; off; off >>= 1) {
    d1 += __shfl_down(d1, off);
    d2 += __shfl_down(d2, off);
  }
  if (l == 0) { f1[row] = d1; f2[row] = d2; }
}

// ---------------- 3. wt[f][k] = bf16(W[k][f]) ----------------
__global__ __launch_bounds__(256) void k_prep_wt(const float* __restrict__ W,
                                                 uint16_t* __restrict__ wt) {
  int idx = blockIdx.x * 256 + threadIdx.x;
  int f  = idx >> 7;
  int k4 = (idx & 127) * 4;
  ushort4 o;
  o.x = f2bf(W[(size_t)(k4 + 0) * FOUT + f]);
  o.y = f2bf(W[(size_t)(k4 + 1) * FOUT + f]);
  o.z = f2bf(W[(size_t)(k4 + 2) * FOUT + f]);
  o.w = f2bf(W[(size_t)(k4 + 3) * FOUT + f]);
  *(ushort4*)(wt + (size_t)f * FIN + k4) = o;
}

// ---------------- 4. ht = (x @ W)^T (bf16 MFMA), 256 blocks ----------------
// grid (128,2): 64 rows x 128 feats per block; 256 thr; lds_barrier + reg prefetch.
__global__ __launch_bounds__(256, 2) void k_gemm_h(const float* __restrict__ x,
                                                   const uint16_t* __restrict__ wt,
                                                   uint16_t* __restrict__ ht) {
  __shared__ __align__(16) uint16_t Xs[64][40];
  __shared__ __align__(16) uint16_t Ws[128][40];
  int i0 = blockIdx.x * 64;
  int f0 = blockIdx.y * 128;
  int tid = threadIdx.x;
  int l = tid & 63, w = tid >> 6;
  int q = l >> 4, r16 = l & 15;
  f32x4 acc[4][2];
#pragma unroll
  for (int a = 0; a < 4; a++)
#pragma unroll
    for (int b = 0; b < 2; b++) acc[a][b] = (f32x4)0.f;

  int xr = tid >> 2, xc = (tid & 3) * 8;     // x: 64x32 fp32, 2 f32x4/thread
  int wr = tid >> 1, wc = (tid & 1) * 16;    // wt: 128x32 bf16, 32B/thread
  const float* xp = x + (size_t)(i0 + xr) * FIN + xc;
  const uint16_t* wp = wt + (size_t)(f0 + wr) * FIN + wc;

  f32x4 u0 = *(const f32x4*)xp;
  f32x4 u1 = *(const f32x4*)(xp + 4);
  uint4 wA = *(const uint4*)wp;
  uint4 wB = *(const uint4*)(wp + 8);

  const int GI = FIN / BK;  // 16
  for (int s = 0; s < GI; s++) {
    // issue next-tile loads (stay in flight across lds_barrier)
    int sn = (s + 1 < GI) ? (s + 1) : s;
    f32x4 u0n = *(const f32x4*)(xp + sn * BK);
    f32x4 u1n = *(const f32x4*)(xp + sn * BK + 4);
    uint4 wAn = *(const uint4*)(wp + sn * BK);
    uint4 wBn = *(const uint4*)(wp + sn * BK + 8);

    uint4 pk;
    pk.x = (uint32_t)f2bf(u0[0]) | ((uint32_t)f2bf(u0[1]) << 16);
    pk.y = (uint32_t)f2bf(u0[2]) | ((uint32_t)f2bf(u0[3]) << 16);
    pk.z = (uint32_t)f2bf(u1[0]) | ((uint32_t)f2bf(u1[1]) << 16);
    pk.w = (uint32_t)f2bf(u1[2]) | ((uint32_t)f2bf(u1[3]) << 16);
    *(uint4*)(&Xs[xr][xc]) = pk;
    *(uint4*)(&Ws[wr][wc]) = wA;
    *(uint4*)(&Ws[wr][wc + 8]) = wB;
    lds_barrier();

    s16x8 Af[4], Bf[2];
#pragma unroll
    for (int a = 0; a < 4; a++) Af[a] = *(const s16x8*)(&Xs[a * 16 + r16][q * 8]);
#pragma unroll
    for (int b = 0; b < 2; b++) Bf[b] = *(const s16x8*)(&Ws[w * 32 + b * 16 + r16][q * 8]);
#pragma unroll
    for (int a = 0; a < 4; a++)
#pragma unroll
      for (int b = 0; b < 2; b++)
        acc[a][b] = __builtin_amdgcn_mfma_f32_16x16x32_bf16(Af[a], Bf[b], acc[a][b], 0, 0, 0);
    lds_barrier();
    u0 = u0n; u1 = u1n; wA = wAn; wB = wBn;
  }

#pragma unroll
  for (int a = 0; a < 4; a++)
#pragma unroll
    for (int b = 0; b < 2; b++) {
      int f = f0 + w * 32 + b * 16 + r16;
      int i = i0 + a * 16 + q * 4;
      ushort4 o;
      o.x = f2bf(acc[a][b][0]); o.y = f2bf(acc[a][b][1]);
      o.z = f2bf(acc[a][b][2]); o.w = f2bf(acc[a][b][3]);
      *(ushort4*)(ht + (size_t)f * NN + i) = o;
    }
}

// ---------------- 5. zero the softmax denominators ----------------
__global__ __launch_bounds__(256) void k_zero(float* __restrict__ l_arr) {
  l_arr[blockIdx.x * 256 + threadIdx.x] = 0.f;
}

// ---------------- 6. fused scores -> P(bf16) -> P @ h, dbuf + lds_barrier ----------------
// 256 thr (4 waves), BM=64, BN=256 (wave w -> feats w*64..+63), BK=32, KSPLIT=8.
// Tile s+2 loads issued at iter s, consumed at stage phase of iter s+1:
// load->use distance >= one full iteration, and lds_barrier never drains vmcnt.
__global__ __launch_bounds__(256, 2) void k_att(const int* __restrict__ adj,
                                                const uint16_t* __restrict__ ht,
                                                const float* __restrict__ f1,
                                                const float* __restrict__ f2,
                                                float* __restrict__ l_arr,
                                                float* __restrict__ part) {
  __shared__ __align__(16) uint16_t Ps[2][64][40];    // 10 KB
  __shared__ __align__(16) uint16_t Hs[2][256][40];   // 40 KB
  __shared__ __align__(16) float Fs[KSLICE];          // 4 KB
  const int i0 = blockIdx.x * 64;
  const int jbase = blockIdx.y * KSLICE;
  const int tid = threadIdx.x;
  const int l = tid & 63, w = tid >> 6;
  const int q = l >> 4, r16 = l & 15;
  const int pr = tid >> 2, pc = tid & 3;

  *(f32x4*)(&Fs[tid * 4]) = *(const f32x4*)(f2 + jbase + tid * 4);

  const float f1i = f1[i0 + pr];
  float lsum = 0.f;
  f32x4 acc[4][4];
#pragma unroll
  for (int a = 0; a < 4; a++)
#pragma unroll
    for (int b = 0; b < 4; b++) acc[a][b] = (f32x4)0.f;

  const int* adjp = adj + (size_t)(i0 + pr) * NN + jbase + pc * 8;
  const uint16_t* htp = ht + (size_t)tid * NN + jbase;   // thread = feature row

  int4 adjR[2][2];
  uint4 hR[2][4];

#define LOADT(t, p) do {                                      \
    const int* ap_ = adjp + (t) * BK;                         \
    adjR[p][0] = *(const int4*)ap_;                           \
    adjR[p][1] = *(const int4*)(ap_ + 4);                     \
    const uint16_t* hp_ = htp + (t) * BK;                     \
    hR[p][0] = *(const uint4*)(hp_);                          \
    hR[p][1] = *(const uint4*)(hp_ + 8);                      \
    hR[p][2] = *(const uint4*)(hp_ + 16);                     \
    hR[p][3] = *(const uint4*)(hp_ + 24);                     \
  } while (0)

#define STAGET(t, p, bf) do {                                 \
    f32x4 F0_ = *(const f32x4*)(&Fs[(t) * BK + pc * 8]);      \
    f32x4 F1_ = *(const f32x4*)(&Fs[(t) * BK + pc * 8 + 4]);  \
    s16x8 pv_;                                                \
    const int* av_ = (const int*)&adjR[p][0];                 \
    _Pragma("unroll")                                         \
    for (int i_ = 0; i_ < 8; i_++) {                          \
      float fj_ = (i_ < 4) ? F0_[i_] : F1_[i_ - 4];           \
      float s_ = f1i + fj_;                                   \
      float e_ = fmaxf(s_, ALPHA * s_);                       \
      float p_ = (av_[i_] != 0) ? __expf(e_) : 1.0f;          \
      lsum += p_;                                             \
      pv_[i_] = (short)f2bf(p_);                              \
    }                                                         \
    *(s16x8*)(&Ps[bf][pr][pc * 8]) = pv_;                     \
    *(uint4*)(&Hs[bf][tid][0])  = hR[p][0];                   \
    *(uint4*)(&Hs[bf][tid][8])  = hR[p][1];                   \
    *(uint4*)(&Hs[bf][tid][16]) = hR[p][2];                   \
    *(uint4*)(&Hs[bf][tid][24]) = hR[p][3];                   \
  } while (0)

  lds_barrier();           // Fs visible
  LOADT(0, 0);
  STAGET(0, 0, 0);
  LOADT(1, 1);
  lds_barrier();           // buf0 ready

  for (int s = 0; s < ITERS; s++) {
    int par = s & 1;
    if (s + 2 < ITERS) LOADT(s + 2, par);   // into set freed by stage at s-1

    s16x8 Af[4], Bf[4];
#pragma unroll
    for (int a = 0; a < 4; a++) Af[a] = *(const s16x8*)(&Ps[par][a * 16 + r16][q * 8]);
#pragma unroll
    for (int b = 0; b < 4; b++) Bf[b] = *(const s16x8*)(&Hs[par][w * 64 + b * 16 + r16][q * 8]);
#pragma unroll
    for (int a = 0; a < 4; a++)
#pragma unroll
      for (int b = 0; b < 4; b++)
        acc[a][b] = __builtin_amdgcn_mfma_f32_16x16x32_bf16(Af[a], Bf[b], acc[a][b], 0, 0, 0);

    if (s + 1 < ITERS) {
      STAGET(s + 1, (s + 1) & 1, (s + 1) & 1);
      lds_barrier();
    }
  }
#undef LOADT
#undef STAGET

  // denominator: reduce over the 4 lanes sharing pr, one atomic per row/block
  lsum += __shfl_down(lsum, 2);
  lsum += __shfl_down(lsum, 1);
  if (pc == 0) atomicAdd(&l_arr[i0 + pr], lsum);

  // part is column-major [KSPLIT][FOUT][NN] -> float4 stores (4 consecutive rows)
  float* pb = part + (size_t)blockIdx.y * ((size_t)NN * FOUT);
#pragma unroll
  for (int a = 0; a < 4; a++)
#pragma unroll
    for (int b = 0; b < 4; b++) {
      int col = w * 64 + b * 16 + r16;
      int row0 = i0 + a * 16 + q * 4;
      *(f32x4*)(pb + (size_t)col * NN + row0) = acc[a][b];
    }
}

// ---------------- 7. combine split-K partials, /l, ELU, fp32 out ----------------
__global__ __launch_bounds__(256) void k_combine(const float* __restrict__ part,
                                                 const float* __restrict__ l_arr,
                                                 float* __restrict__ out) {
  int t = blockIdx.x * 256 + threadIdx.x;
  int base = t * 4;                  // flat index in [FOUT][NN]
  int col = base >> 13;              // / NN
  int row0 = base & (NN - 1);
  f32x4 sum = (f32x4)0.f;
#pragma unroll
  for (int p = 0; p < KSPLIT; p++)
    sum += *(const f32x4*)(part + (size_t)p * NN * FOUT + base);
  f32x4 lv = *(const f32x4*)(l_arr + row0);
#pragma unroll
  for (int i = 0; i < 4; i++) {
    float v = sum[i] / lv[i];
    float e = v > 0.f ? v : (__expf(v) - 1.f);
    out[(size_t)(row0 + i) * FOUT + col] = e;
  }
}

extern "C" void kernel_launch(void* const* d_in, const int* in_sizes, int n_in,
                              void* d_out, int out_size, void* d_ws, size_t ws_size,
                              hipStream_t stream) {
  const float* x   = (const float*)d_in[0];
  const int*   adj = (const int*)d_in[1];
  const float* W   = (const float*)d_in[2];
  const float* a   = (const float*)d_in[3];
  float* out = (float*)d_out;

  char* ws = (char*)d_ws;
  float*    wa1   = (float*)ws;                        // 512 f32
  float*    wa2   = wa1 + 512;                         // 512 f32
  float*    f1    = wa2 + 512;                         // 8192 f32
  float*    f2    = f1 + NN;                           // 8192 f32
  float*    l_arr = f2 + NN;                           // 8192 f32
  uint16_t* wt    = (uint16_t*)(l_arr + NN);           // 256*512 bf16
  uint16_t* ht    = wt + (size_t)FOUT * FIN;           // 256*8192 bf16 (4 MB)
  float*    part  = (float*)(ht + (size_t)NN * FOUT);  // KSPLIT * 256*8192 f32 (64 MB)

  k_wa<<<2, 256, 0, stream>>>(W, a, wa1, wa2);
  k_prep_wt<<<128, 256, 0, stream>>>(W, wt);
  k_f1f2<<<NN / 4, 256, 0, stream>>>(x, wa1, wa2, f1, f2);
  k_zero<<<NN / 256, 256, 0, stream>>>(l_arr);
  k_gemm_h<<<dim3(128, 2), 256, 0, stream>>>(x, wt, ht);
  k_att<<<dim3(NN / 64, KSPLIT), 256, 0, stream>>>(adj, ht, f1, f2, l_arr, part);
  k_combine<<<NN * FOUT / 1024, 256, 0, stream>>>(part, l_arr, out);
}